// Round 8
// baseline (948.999 us; speedup 1.0000x reference)
//
#include <hip/hip_runtime.h>

#define FIN 128
#define FH  16
#define FO  64
#define GB  128        // nodes per bucket (pow2: bucket = dst>>7)
#define MAXNB 1024     // max buckets (N <= 131072)
#define CHUNK 8192     // edges per block in bscatter

__device__ __forceinline__ unsigned pack_bf16x2(float a, float b) {
    unsigned ua = __float_as_uint(a), ub = __float_as_uint(b);
    ua = (ua + 0x7fffu + ((ua >> 16) & 1u)) >> 16;          // RNE
    ub = (ub + 0x7fffu + ((ub >> 16) & 1u)) >> 16;
    return ua | (ub << 16);
}

__device__ __forceinline__ float2 unpack_bf16x2(unsigned u) {
    float2 r;
    r.x = __uint_as_float(u << 16);
    r.y = __uint_as_float(u & 0xffff0000u);
    return r;
}

// ---------- A1: bucket histogram (LDS-aggregated) ----------
__global__ __launch_bounds__(256) void k_bhist(const int* __restrict__ dst,
                                               int* __restrict__ bcnt, int E, int nb) {
    __shared__ int h[MAXNB];
    int t = threadIdx.x;
    for (int i = t; i < nb; i += 256) h[i] = 0;
    __syncthreads();
    int stride = gridDim.x * 256;
    for (int e = blockIdx.x * 256 + t; e < E; e += stride)
        atomicAdd(&h[dst[e] >> 7], 1);
    __syncthreads();
    for (int i = t; i < nb; i += 256)
        if (h[i]) atomicAdd(&bcnt[i], h[i]);
}

// ---------- A2: single-block exclusive scan of bucket counts ----------
__global__ __launch_bounds__(1024) void k_bscan(const int* __restrict__ bcnt,
                                                int* __restrict__ bstart,
                                                int* __restrict__ bfill, int nb) {
    __shared__ int s[1024];
    int t = threadIdx.x;
    int v = (t < nb) ? bcnt[t] : 0;
    s[t] = v;
    __syncthreads();
    for (int off = 1; off < 1024; off <<= 1) {
        int u = (t >= off) ? s[t - off] : 0;
        __syncthreads();
        s[t] += u;
        __syncthreads();
    }
    if (t < nb) { bstart[t] = s[t] - v; bfill[t] = s[t] - v; }
    if (t == nb - 1) bstart[nb] = s[t];
}

// ---------- A3: chunk-local LDS bucket-sort, contiguous run write-out ----------
// pack: (dst & 127) << 17 | src   (src < 2^17)
__global__ __launch_bounds__(256) void k_bscatter(const int* __restrict__ src,
                                                  const int* __restrict__ dst,
                                                  int* __restrict__ bfill,
                                                  int* __restrict__ bedge, int E) {
    __shared__ int h[MAXNB];      // chunk bucket counts -> fill counters (4 KB)
    __shared__ int scanp[256];    // 1 KB
    __shared__ int stage[CHUNK];  // 32 KB
    int t = threadIdx.x;
    int c0 = blockIdx.x * CHUNK;
    int c1 = min(c0 + CHUNK, E);

    // 1) chunk histogram
    for (int i = t; i < MAXNB; i += 256) h[i] = 0;
    __syncthreads();
    for (int e = c0 + t; e < c1; e += 256)
        atomicAdd(&h[dst[e] >> 7], 1);
    __syncthreads();

    // 2) exclusive scan of 1024 counts (4/thread + Hillis-Steele over 256)
    int b0 = 4 * t;
    int a0 = h[b0], a1 = h[b0 + 1], a2 = h[b0 + 2], a3 = h[b0 + 3];
    int s4 = a0 + a1 + a2 + a3;
    scanp[t] = s4;
    __syncthreads();
    for (int off = 1; off < 256; off <<= 1) {
        int u = (t >= off) ? scanp[t - off] : 0;
        __syncthreads();
        scanp[t] += u;
        __syncthreads();
    }
    int pt = scanp[t] - s4;
    int lo0 = pt, lo1 = pt + a0, lo2 = pt + a0 + a1, lo3 = pt + a0 + a1 + a2;
    int hi3 = pt + s4;

    // 3) reserve global ranges (bases stay in registers), set chunk-local fill
    int g0 = 0, g1 = 0, g2 = 0, g3 = 0;
    if (a0) g0 = atomicAdd(&bfill[b0],     a0) - lo0;
    if (a1) g1 = atomicAdd(&bfill[b0 + 1], a1) - lo1;
    if (a2) g2 = atomicAdd(&bfill[b0 + 2], a2) - lo2;
    if (a3) g3 = atomicAdd(&bfill[b0 + 3], a3) - lo3;
    h[b0] = lo0; h[b0 + 1] = lo1; h[b0 + 2] = lo2; h[b0 + 3] = lo3;
    __syncthreads();

    // 4) place packed edges at chunk-local rank
    for (int e = c0 + t; e < c1; e += 256) {
        int d = dst[e];
        int p = atomicAdd(&h[d >> 7], 1);
        stage[p] = ((d & 127) << 17) | src[e];
    }
    __syncthreads();

    // 5) write-out: each thread streams its own 4 adjacent buckets' runs
    for (int p = lo0; p < lo1; ++p) bedge[g0 + p] = stage[p];
    for (int p = lo1; p < lo2; ++p) bedge[g1 + p] = stage[p];
    for (int p = lo2; p < lo3; ++p) bedge[g2 + p] = stage[p];
    for (int p = lo3; p < hi3; ++p) bedge[g3 + p] = stage[p];
}

// ---------- per-node degree -> dinv (per bucket, from bedge) ----------
__global__ __launch_bounds__(256) void k_ndeg(const int* __restrict__ bstart,
                                              const int* __restrict__ bedge,
                                              float* __restrict__ dinv, int N) {
    __shared__ int cnt[GB];
    int t = threadIdx.x, b = blockIdx.x;
    int base = b << 7;
    if (t < GB) cnt[t] = 0;
    __syncthreads();
    int ebeg = bstart[b], eend = bstart[b + 1];
    for (int e = ebeg + t; e < eend; e += 256)
        atomicAdd(&cnt[bedge[e] >> 17], 1);
    __syncthreads();
    if (t < GB && base + t < N) dinv[base + t] = rsqrtf((float)(cnt[t] + 1));
}

// ---------- layer 1 transform: hs1 = bf16((x @ W1) * dinv) ----------
__global__ __launch_bounds__(256) void k_gemm1(const float* __restrict__ x,
                                               const float* __restrict__ W1,
                                               const float* __restrict__ dinv,
                                               unsigned* __restrict__ hs1u, int n) {
    __shared__ float w[FIN * FH];  // 8 KB
    int t = threadIdx.x;
    for (int i = t; i < FIN * FH; i += 256) w[i] = W1[i];
    __syncthreads();
    int r = t >> 4, j = t & 15;
    int row = blockIdx.x * 16 + r;
    if (row >= n) return;
    const float* xr = x + (long long)row * FIN;
    float acc = 0.0f;
#pragma unroll 8
    for (int k = 0; k < FIN; ++k) acc = fmaf(xr[k], w[k * FH + j], acc);
    float v = acc * dinv[row];
    float v_hi = __shfl_xor(v, 1, 64);   // partner feature j^1
    if ((j & 1) == 0) hs1u[row * 8 + (j >> 1)] = pack_bf16x2(v, v_hi);
}

// ---------- layer 1: bucket aggregation + relu + bias, pre-scaled (bf16 out) ----------
__global__ __launch_bounds__(256) void k_gather1b(const int* __restrict__ bstart,
                                                  const int* __restrict__ bedge,
                                                  const unsigned* __restrict__ hs1u,
                                                  const float* __restrict__ dinv,
                                                  const float* __restrict__ b1,
                                                  unsigned* __restrict__ h1su, int N) {
    __shared__ float acc[GB * FH];   // 8 KB
    int t = threadIdx.x, b = blockIdx.x;
    int base = b << 7;
    int nn = min(GB, N - base);
    // init accumulators from self-loop rows (already dinv[src]-scaled)
    for (int i = t; i < GB * 8; i += 256) {
        int node = i >> 3, f2 = i & 7;
        float2 p = make_float2(0.f, 0.f);
        if (node < nn) p = unpack_bf16x2(hs1u[(base + node) * 8 + f2]);
        acc[node * 16 + 2 * f2] = p.x;
        acc[node * 16 + 2 * f2 + 1] = p.y;
    }
    __syncthreads();
    int ebeg = bstart[b], eend = bstart[b + 1];
    int f = t & 15;
    for (int e = ebeg + (t >> 4); e < eend; e += 16) {
        int v = bedge[e];
        int ld = v >> 17, s = v & 0x1FFFF;
        unsigned u = hs1u[s * 8 + (f >> 1)];
        float val = __uint_as_float((f & 1) ? (u & 0xffff0000u) : (u << 16));
        atomicAdd(&acc[ld * 16 + f], val);
    }
    __syncthreads();
    // finalize: thread -> node t>>1, dword range (t&1)*4..+4
    int node = t >> 1;
    if (node < nn) {
        float di = dinv[base + node];
        int f2o = (t & 1) * 4;
        unsigned o[4];
#pragma unroll
        for (int k = 0; k < 4; ++k) {
            int f2k = f2o + k;
            float v0 = fmaxf(fmaf(di, acc[node * 16 + 2 * f2k],     b1[2 * f2k]),     0.f) * di;
            float v1 = fmaxf(fmaf(di, acc[node * 16 + 2 * f2k + 1], b1[2 * f2k + 1]), 0.f) * di;
            o[k] = pack_bf16x2(v0, v1);
        }
#pragma unroll
        for (int k = 0; k < 4; ++k) h1su[(base + node) * 8 + f2o + k] = o[k];
    }
}

// ---------- layer 2: bucket aggregation + (g @ W2)*dinv + b2 -> log_softmax ----------
__global__ __launch_bounds__(256) void k_gather2b(const int* __restrict__ bstart,
                                                  const int* __restrict__ bedge,
                                                  const unsigned* __restrict__ h1su,
                                                  const float* __restrict__ dinv,
                                                  const float* __restrict__ W2,
                                                  const float* __restrict__ b2,
                                                  float* __restrict__ out, int N) {
    __shared__ float acc[GB * FH];   // 8 KB
    __shared__ float w2[FH * FO];    // 4 KB
    int t = threadIdx.x, b = blockIdx.x;
    int base = b << 7;
    int nn = min(GB, N - base);
    for (int i = t; i < FH * FO; i += 256) w2[i] = W2[i];
    for (int i = t; i < GB * 8; i += 256) {
        int node = i >> 3, f2 = i & 7;
        float2 p = make_float2(0.f, 0.f);
        if (node < nn) p = unpack_bf16x2(h1su[(base + node) * 8 + f2]);
        acc[node * 16 + 2 * f2] = p.x;
        acc[node * 16 + 2 * f2 + 1] = p.y;
    }
    __syncthreads();
    int ebeg = bstart[b], eend = bstart[b + 1];
    int f = t & 15;
    for (int e = ebeg + (t >> 4); e < eend; e += 16) {
        int v = bedge[e];
        int ld = v >> 17, s = v & 0x1FFFF;
        unsigned u = h1su[s * 8 + (f >> 1)];
        float val = __uint_as_float((f & 1) ? (u & 0xffff0000u) : (u << 16));
        atomicAdd(&acc[ld * 16 + f], val);
    }
    __syncthreads();
    // finalize: one wave per node (4 waves round-robin over 128 nodes)
    int lane = t & 63, wv = t >> 6;
    for (int ni = wv; ni < nn; ni += 4) {
        float o = 0.f;
#pragma unroll
        for (int j = 0; j < FH; ++j) o = fmaf(acc[ni * 16 + j], w2[j * FO + lane], o);
        float v = fmaf(dinv[base + ni], o, b2[lane]);
        float m = v;
#pragma unroll
        for (int off = 32; off >= 1; off >>= 1) m = fmaxf(m, __shfl_xor(m, off, 64));
        float ex = __expf(v - m);
#pragma unroll
        for (int off = 32; off >= 1; off >>= 1) ex += __shfl_xor(ex, off, 64);
        out[(base + ni) * FO + lane] = v - m - __logf(ex);
    }
}

extern "C" void kernel_launch(void* const* d_in, const int* in_sizes, int n_in,
                              void* d_out, int out_size, void* d_ws, size_t ws_size,
                              hipStream_t stream) {
    const float* x  = (const float*)d_in[0];
    const int*   ei = (const int*)d_in[1];
    const float* W1 = (const float*)d_in[2];
    const float* b1 = (const float*)d_in[3];
    const float* W2 = (const float*)d_in[4];
    const float* b2 = (const float*)d_in[5];
    float* out = (float*)d_out;

    int N = in_sizes[0] / FIN;   // 100000
    int E = in_sizes[1] / 2;     // 3200000
    const int* src = ei;
    const int* dst = ei + E;
    int nb = (N + GB - 1) / GB;  // 782

    // workspace (4B units): bcnt[1024] | bstart[1025] | bfill[1024] | bedge[E]
    //                       | dinv[N] | hs1u[8N] | h1su[8N]
    int* bcnt       = (int*)d_ws;
    int* bstart     = bcnt + MAXNB;
    int* bfill      = bstart + MAXNB + 1;
    int* bedge      = bfill + MAXNB;
    float* dinv     = (float*)(bedge + E);
    unsigned* hs1u  = (unsigned*)(dinv + N);
    unsigned* h1su  = hs1u + 8LL * N;

    hipMemsetAsync(bcnt, 0, MAXNB * sizeof(int), stream);
    k_bhist<<<256, 256, 0, stream>>>(dst, bcnt, E, nb);
    k_bscan<<<1, 1024, 0, stream>>>(bcnt, bstart, bfill, nb);
    k_bscatter<<<(E + CHUNK - 1) / CHUNK, 256, 0, stream>>>(src, dst, bfill, bedge, E);
    k_ndeg<<<nb, 256, 0, stream>>>(bstart, bedge, dinv, N);

    k_gemm1<<<(N + 15) / 16, 256, 0, stream>>>(x, W1, dinv, hs1u, N);
    k_gather1b<<<nb, 256, 0, stream>>>(bstart, bedge, hs1u, dinv, b1, h1su, N);
    k_gather2b<<<nb, 256, 0, stream>>>(bstart, bedge, h1su, dinv, W2, b2, out, N);
}

// Round 9
// 349.957 us; speedup vs baseline: 2.7118x; 2.7118x over previous
//
#include <hip/hip_runtime.h>

#define FIN 128
#define FH  16
#define FO  64
#define GB  128        // nodes per bucket (pow2: bucket = dst>>7)
#define MAXNB 1024     // max buckets (N <= 131072)
#define CHUNK 8192     // edges per block in bscatter

__device__ __forceinline__ unsigned pack_bf16x2(float a, float b) {
    unsigned ua = __float_as_uint(a), ub = __float_as_uint(b);
    ua = (ua + 0x7fffu + ((ua >> 16) & 1u)) >> 16;          // RNE
    ub = (ub + 0x7fffu + ((ub >> 16) & 1u)) >> 16;
    return ua | (ub << 16);
}

__device__ __forceinline__ float2 unpack_bf16x2(unsigned u) {
    float2 r;
    r.x = __uint_as_float(u << 16);
    r.y = __uint_as_float(u & 0xffff0000u);
    return r;
}

// ---------- A1: bucket histogram (LDS-aggregated) ----------
__global__ __launch_bounds__(256) void k_bhist(const int* __restrict__ dst,
                                               int* __restrict__ bcnt, int E, int nb) {
    __shared__ int h[MAXNB];
    int t = threadIdx.x;
    for (int i = t; i < nb; i += 256) h[i] = 0;
    __syncthreads();
    int stride = gridDim.x * 256;
    for (int e = blockIdx.x * 256 + t; e < E; e += stride)
        atomicAdd(&h[dst[e] >> 7], 1);
    __syncthreads();
    for (int i = t; i < nb; i += 256)
        if (h[i]) atomicAdd(&bcnt[i], h[i]);
}

// ---------- A2: single-block exclusive scan of bucket counts ----------
__global__ __launch_bounds__(1024) void k_bscan(const int* __restrict__ bcnt,
                                                int* __restrict__ bstart,
                                                int* __restrict__ bfill, int nb) {
    __shared__ int s[1024];
    int t = threadIdx.x;
    int v = (t < nb) ? bcnt[t] : 0;
    s[t] = v;
    __syncthreads();
    for (int off = 1; off < 1024; off <<= 1) {
        int u = (t >= off) ? s[t - off] : 0;
        __syncthreads();
        s[t] += u;
        __syncthreads();
    }
    if (t < nb) { bstart[t] = s[t] - v; bfill[t] = s[t] - v; }
    if (t == nb - 1) bstart[nb] = s[t];
}

// ---------- A3: chunk-local LDS bucket-sort, contiguous run write-out ----------
// pack: (dst & 127) << 17 | src   (src < 2^17)
__global__ __launch_bounds__(256) void k_bscatter(const int* __restrict__ src,
                                                  const int* __restrict__ dst,
                                                  int* __restrict__ bfill,
                                                  int* __restrict__ bedge, int E) {
    __shared__ int h[MAXNB];      // chunk bucket counts -> fill counters (4 KB)
    __shared__ int scanp[256];    // 1 KB
    __shared__ int stage[CHUNK];  // 32 KB
    int t = threadIdx.x;
    int c0 = blockIdx.x * CHUNK;
    int c1 = min(c0 + CHUNK, E);

    // 1) chunk histogram
    for (int i = t; i < MAXNB; i += 256) h[i] = 0;
    __syncthreads();
    for (int e = c0 + t; e < c1; e += 256)
        atomicAdd(&h[dst[e] >> 7], 1);
    __syncthreads();

    // 2) exclusive scan of 1024 counts (4/thread + Hillis-Steele over 256)
    int b0 = 4 * t;
    int a0 = h[b0], a1 = h[b0 + 1], a2 = h[b0 + 2], a3 = h[b0 + 3];
    int s4 = a0 + a1 + a2 + a3;
    scanp[t] = s4;
    __syncthreads();
    for (int off = 1; off < 256; off <<= 1) {
        int u = (t >= off) ? scanp[t - off] : 0;
        __syncthreads();
        scanp[t] += u;
        __syncthreads();
    }
    int pt = scanp[t] - s4;
    int lo0 = pt, lo1 = pt + a0, lo2 = pt + a0 + a1, lo3 = pt + a0 + a1 + a2;
    int hi3 = pt + s4;

    // 3) reserve global ranges (bases stay in registers), set chunk-local fill
    int g0 = 0, g1 = 0, g2 = 0, g3 = 0;
    if (a0) g0 = atomicAdd(&bfill[b0],     a0) - lo0;
    if (a1) g1 = atomicAdd(&bfill[b0 + 1], a1) - lo1;
    if (a2) g2 = atomicAdd(&bfill[b0 + 2], a2) - lo2;
    if (a3) g3 = atomicAdd(&bfill[b0 + 3], a3) - lo3;
    h[b0] = lo0; h[b0 + 1] = lo1; h[b0 + 2] = lo2; h[b0 + 3] = lo3;
    __syncthreads();

    // 4) place packed edges at chunk-local rank
    for (int e = c0 + t; e < c1; e += 256) {
        int d = dst[e];
        int p = atomicAdd(&h[d >> 7], 1);
        stage[p] = ((d & 127) << 17) | src[e];
    }
    __syncthreads();

    // 5) write-out: each thread streams its own 4 adjacent buckets' runs
    for (int p = lo0; p < lo1; ++p) bedge[g0 + p] = stage[p];
    for (int p = lo1; p < lo2; ++p) bedge[g1 + p] = stage[p];
    for (int p = lo2; p < lo3; ++p) bedge[g2 + p] = stage[p];
    for (int p = lo3; p < hi3; ++p) bedge[g3 + p] = stage[p];
}

// ---------- B: per-bucket node sort (stage-free): bedge -> sorted_src + CSR + dinv ----------
// One block per bucket; the bucket's output segment is written by exactly one
// block (one XCD), so random stores within the 16 KB segment coalesce in L2.
__global__ __launch_bounds__(256) void k_nsort(const int* __restrict__ bstart,
                                               const int* __restrict__ bedge,
                                               int* __restrict__ sorted_src,
                                               int* __restrict__ counts,
                                               int* __restrict__ row_start,
                                               float* __restrict__ dinv, int N) {
    __shared__ int hist[GB];
    __shared__ int fill[GB];
    int t = threadIdx.x, b = blockIdx.x;
    int base = b << 7;
    int nn = min(GB, N - base);
    if (nn <= 0) return;
    int ebeg = bstart[b], eend = bstart[b + 1];
    if (t < GB) hist[t] = 0;
    __syncthreads();
    for (int e = ebeg + t; e < eend; e += 256)
        atomicAdd(&hist[bedge[e] >> 17], 1);
    __syncthreads();
    int c = (t < GB) ? hist[t] : 0;
    for (int off = 1; off < GB; off <<= 1) {
        int u = (t < GB && t >= off) ? hist[t - off] : 0;
        __syncthreads();
        if (t < GB) hist[t] += u;
        __syncthreads();
    }
    int excl = (t < GB) ? hist[t] - c : 0;
    if (t < nn) {
        counts[base + t] = c;
        row_start[base + t] = ebeg + excl;
        dinv[base + t] = rsqrtf((float)(c + 1));
        fill[t] = ebeg + excl;
    }
    __syncthreads();
    for (int e = ebeg + t; e < eend; e += 256) {
        int v = bedge[e];
        int p = atomicAdd(&fill[v >> 17], 1);
        sorted_src[p] = v & 0x1FFFF;
    }
}

// ---------- layer 1 transform: hs1 = bf16((x @ W1) * dinv) ----------
__global__ __launch_bounds__(256) void k_gemm1(const float* __restrict__ x,
                                               const float* __restrict__ W1,
                                               const float* __restrict__ dinv,
                                               unsigned* __restrict__ hs1u, int n) {
    __shared__ float w[FIN * FH];  // 8 KB
    int t = threadIdx.x;
    for (int i = t; i < FIN * FH; i += 256) w[i] = W1[i];
    __syncthreads();
    int r = t >> 4, j = t & 15;
    int row = blockIdx.x * 16 + r;
    if (row >= n) return;
    const float* xr = x + (long long)row * FIN;
    float acc = 0.0f;
#pragma unroll 8
    for (int k = 0; k < FIN; ++k) acc = fmaf(xr[k], w[k * FH + j], acc);
    float v = acc * dinv[row];
    float v_hi = __shfl_xor(v, 1, 64);   // partner feature j^1
    if ((j & 1) == 0) hs1u[row * 8 + (j >> 1)] = pack_bf16x2(v, v_hi);
}

// ---------- layer 1 gather + relu + bias, pre-scaled for layer 2 (bf16 rows) ----------
__global__ __launch_bounds__(256) void k_gather1(const int* __restrict__ rs,
                                                 const int* __restrict__ cnt,
                                                 const int* __restrict__ ss,
                                                 const unsigned* __restrict__ hs1u,
                                                 const float* __restrict__ dinv,
                                                 const float* __restrict__ b1,
                                                 unsigned* __restrict__ h1su, int n) {
    int t = threadIdx.x;
    int lane = t & 63, g8 = lane >> 3, f2 = lane & 7;
    int node = blockIdx.x * 4 + (t >> 6);
    if (node >= n) return;
    int beg = rs[node], end = beg + cnt[node];
    float ax = 0.0f, ay = 0.0f;
    int e = beg + g8;
    for (; e + 8 < end; e += 16) {
        unsigned u0 = hs1u[ss[e] * 8 + f2];
        unsigned u1 = hs1u[ss[e + 8] * 8 + f2];
        float2 p0 = unpack_bf16x2(u0);
        float2 p1 = unpack_bf16x2(u1);
        ax += p0.x + p1.x; ay += p0.y + p1.y;
    }
    if (e < end) {
        float2 p = unpack_bf16x2(hs1u[ss[e] * 8 + f2]);
        ax += p.x; ay += p.y;
    }
#pragma unroll
    for (int off = 8; off <= 32; off <<= 1) {
        ax += __shfl_xor(ax, off, 64);
        ay += __shfl_xor(ay, off, 64);
    }
    float2 s = unpack_bf16x2(hs1u[node * 8 + f2]);  // self-loop
    ax += s.x; ay += s.y;
    float di = dinv[node];
    float v0 = fmaxf(fmaf(di, ax, b1[2 * f2]), 0.0f) * di;
    float v1 = fmaxf(fmaf(di, ay, b1[2 * f2 + 1]), 0.0f) * di;
    if (lane < 8) h1su[node * 8 + f2] = pack_bf16x2(v0, v1);
}

// ---------- layer 2: bf16 gather, fused (g @ W2)*dinv + b2 -> log_softmax ----------
__global__ __launch_bounds__(256) void k_agg2f(const int* __restrict__ rs,
                                               const int* __restrict__ cnt,
                                               const int* __restrict__ ss,
                                               const unsigned* __restrict__ h1su,
                                               const float* __restrict__ dinv,
                                               const float* __restrict__ W2,
                                               const float* __restrict__ b2,
                                               float* __restrict__ out, int n) {
    int t = threadIdx.x;
    int lane = t & 63, g8 = lane >> 3, f2 = lane & 7;
    int node = blockIdx.x * 4 + (t >> 6);
    if (node >= n) return;
    float w[FH];  // W2 column `lane`
#pragma unroll
    for (int j = 0; j < FH; ++j) w[j] = W2[j * FO + lane];
    int beg = rs[node], end = beg + cnt[node];
    float ax = 0.0f, ay = 0.0f;
    int e = beg + g8;
    for (; e + 8 < end; e += 16) {
        unsigned u0 = h1su[ss[e] * 8 + f2];
        unsigned u1 = h1su[ss[e + 8] * 8 + f2];
        float2 p0 = unpack_bf16x2(u0);
        float2 p1 = unpack_bf16x2(u1);
        ax += p0.x + p1.x; ay += p0.y + p1.y;
    }
    if (e < end) {
        float2 p = unpack_bf16x2(h1su[ss[e] * 8 + f2]);
        ax += p.x; ay += p.y;
    }
#pragma unroll
    for (int off = 8; off <= 32; off <<= 1) {
        ax += __shfl_xor(ax, off, 64);
        ay += __shfl_xor(ay, off, 64);
    }
    float2 s = unpack_bf16x2(h1su[node * 8 + f2]);  // self-loop
    ax += s.x; ay += s.y;
    // lane f2 holds pair (g[2f2], g[2f2+1]) in every 8-lane segment; 16 -> 64
    float o = 0.0f;
#pragma unroll
    for (int j = 0; j < 8; ++j) {
        o = fmaf(__shfl(ax, j, 8), w[2 * j], o);
        o = fmaf(__shfl(ay, j, 8), w[2 * j + 1], o);
    }
    float v = fmaf(dinv[node], o, b2[lane]);
    float m = v;
#pragma unroll
    for (int off = 32; off >= 1; off >>= 1) m = fmaxf(m, __shfl_xor(m, off, 64));
    float ex = __expf(v - m);
#pragma unroll
    for (int off = 32; off >= 1; off >>= 1) ex += __shfl_xor(ex, off, 64);
    out[node * FO + lane] = v - m - __logf(ex);
}

extern "C" void kernel_launch(void* const* d_in, const int* in_sizes, int n_in,
                              void* d_out, int out_size, void* d_ws, size_t ws_size,
                              hipStream_t stream) {
    const float* x  = (const float*)d_in[0];
    const int*   ei = (const int*)d_in[1];
    const float* W1 = (const float*)d_in[2];
    const float* b1 = (const float*)d_in[3];
    const float* W2 = (const float*)d_in[4];
    const float* b2 = (const float*)d_in[5];
    float* out = (float*)d_out;

    int N = in_sizes[0] / FIN;   // 100000
    int E = in_sizes[1] / 2;     // 3200000
    const int* src = ei;
    const int* dst = ei + E;
    int nb = (N + GB - 1) / GB;  // 782

    // workspace (4B units): bcnt[1024] | bstart[1025] | bfill[1024] | counts[N]
    //   | row_start[N] | sorted_src[E] | bedge[E] | dinv[N] | hs1u[8N] | h1su[8N]
    int* bcnt       = (int*)d_ws;
    int* bstart     = bcnt + MAXNB;
    int* bfill      = bstart + MAXNB + 1;
    int* counts     = bfill + MAXNB;
    int* row_start  = counts + N;
    int* sorted_src = row_start + N;
    int* bedge      = sorted_src + E;
    float* dinv     = (float*)(bedge + E);
    unsigned* hs1u  = (unsigned*)(dinv + N);
    unsigned* h1su  = hs1u + 8LL * N;

    hipMemsetAsync(bcnt, 0, MAXNB * sizeof(int), stream);
    k_bhist<<<256, 256, 0, stream>>>(dst, bcnt, E, nb);
    k_bscan<<<1, 1024, 0, stream>>>(bcnt, bstart, bfill, nb);
    k_bscatter<<<(E + CHUNK - 1) / CHUNK, 256, 0, stream>>>(src, dst, bfill, bedge, E);
    k_nsort<<<nb, 256, 0, stream>>>(bstart, bedge, sorted_src, counts, row_start, dinv, N);

    k_gemm1<<<(N + 15) / 16, 256, 0, stream>>>(x, W1, dinv, hs1u, N);
    k_gather1<<<(N + 3) / 4, 256, 0, stream>>>(row_start, counts, sorted_src, hs1u, dinv, b1, h1su, N);
    k_agg2f<<<(N + 3) / 4, 256, 0, stream>>>(row_start, counts, sorted_src, h1su, dinv, W2, b2, out, N);
}

// Round 10
// 297.090 us; speedup vs baseline: 3.1943x; 1.1780x over previous
//
#include <hip/hip_runtime.h>

#define FIN 128
#define FH  16
#define FO  64
#define GB  128        // nodes per bucket (pow2: bucket = dst>>7)
#define MAXNB 1024     // max buckets (N <= 131072)
#define CHUNK 8192     // edges per block in bscatter

__device__ __forceinline__ unsigned pack_bf16x2(float a, float b) {
    unsigned ua = __float_as_uint(a), ub = __float_as_uint(b);
    ua = (ua + 0x7fffu + ((ua >> 16) & 1u)) >> 16;          // RNE
    ub = (ub + 0x7fffu + ((ub >> 16) & 1u)) >> 16;
    return ua | (ub << 16);
}

__device__ __forceinline__ float2 unpack_bf16x2(unsigned u) {
    float2 r;
    r.x = __uint_as_float(u << 16);
    r.y = __uint_as_float(u & 0xffff0000u);
    return r;
}

// ---------- A1: bucket histogram (LDS-aggregated), 1024 threads ----------
__global__ __launch_bounds__(1024) void k_bhist(const int* __restrict__ dst,
                                                int* __restrict__ bcnt, int E, int nb) {
    __shared__ int h[MAXNB];
    int t = threadIdx.x;
    if (t < nb) h[t] = 0;
    __syncthreads();
    int stride = gridDim.x * 1024;
    for (int e = blockIdx.x * 1024 + t; e < E; e += stride)
        atomicAdd(&h[dst[e] >> 7], 1);
    __syncthreads();
    if (t < nb && h[t]) atomicAdd(&bcnt[t], h[t]);
}

// ---------- A2: single-block exclusive scan of bucket counts ----------
__global__ __launch_bounds__(1024) void k_bscan(const int* __restrict__ bcnt,
                                                int* __restrict__ bstart,
                                                int* __restrict__ bfill, int nb) {
    __shared__ int s[1024];
    int t = threadIdx.x;
    int v = (t < nb) ? bcnt[t] : 0;
    s[t] = v;
    __syncthreads();
    for (int off = 1; off < 1024; off <<= 1) {
        int u = (t >= off) ? s[t - off] : 0;
        __syncthreads();
        s[t] += u;
        __syncthreads();
    }
    if (t < nb) { bstart[t] = s[t] - v; bfill[t] = s[t] - v; }
    if (t == nb - 1) bstart[nb] = s[t];
}

// ---------- A3: chunk-local LDS bucket-sort, 1024 threads (1 bucket/thread) ----------
// pack: (dst & 127) << 17 | src   (src < 2^17)
__global__ __launch_bounds__(1024) void k_bscatter(const int* __restrict__ src,
                                                   const int* __restrict__ dst,
                                                   int* __restrict__ bfill,
                                                   int* __restrict__ bedge, int E) {
    __shared__ int h[MAXNB];      // chunk bucket counts -> fill counters (4 KB)
    __shared__ int scanp[1024];   // 4 KB
    __shared__ int stage[CHUNK];  // 32 KB
    int t = threadIdx.x;
    int c0 = blockIdx.x * CHUNK;
    int c1 = min(c0 + CHUNK, E);

    // 1) chunk histogram
    h[t] = 0;
    __syncthreads();
    for (int e = c0 + t; e < c1; e += 1024)
        atomicAdd(&h[dst[e] >> 7], 1);
    __syncthreads();

    // 2) exclusive scan over 1024 buckets (one per thread)
    int a = h[t];
    scanp[t] = a;
    __syncthreads();
    for (int off = 1; off < 1024; off <<= 1) {
        int u = (t >= off) ? scanp[t - off] : 0;
        __syncthreads();
        scanp[t] += u;
        __syncthreads();
    }
    int lo = scanp[t] - a;
    int hi = lo + a;

    // 3) reserve global range (base in register), set chunk-local fill
    int g = 0;
    if (a) g = atomicAdd(&bfill[t], a) - lo;
    h[t] = lo;
    __syncthreads();

    // 4) place packed edges at chunk-local rank
    for (int e = c0 + t; e < c1; e += 1024) {
        int d = dst[e];
        int p = atomicAdd(&h[d >> 7], 1);
        stage[p] = ((d & 127) << 17) | src[e];
    }
    __syncthreads();

    // 5) write-out: each thread streams its own bucket's run
    for (int p = lo; p < hi; ++p) bedge[g + p] = stage[p];
}

// ---------- B: per-bucket node sort (stage-free): bedge -> sorted_src + CSR + dinv ----------
__global__ __launch_bounds__(256) void k_nsort(const int* __restrict__ bstart,
                                               const int* __restrict__ bedge,
                                               int* __restrict__ sorted_src,
                                               int* __restrict__ counts,
                                               int* __restrict__ row_start,
                                               float* __restrict__ dinv, int N) {
    __shared__ int hist[GB];
    __shared__ int fill[GB];
    int t = threadIdx.x, b = blockIdx.x;
    int base = b << 7;
    int nn = min(GB, N - base);
    if (nn <= 0) return;
    int ebeg = bstart[b], eend = bstart[b + 1];
    if (t < GB) hist[t] = 0;
    __syncthreads();
    for (int e = ebeg + t; e < eend; e += 256)
        atomicAdd(&hist[bedge[e] >> 17], 1);
    __syncthreads();
    int c = (t < GB) ? hist[t] : 0;
    for (int off = 1; off < GB; off <<= 1) {
        int u = (t < GB && t >= off) ? hist[t - off] : 0;
        __syncthreads();
        if (t < GB) hist[t] += u;
        __syncthreads();
    }
    int excl = (t < GB) ? hist[t] - c : 0;
    if (t < nn) {
        counts[base + t] = c;
        row_start[base + t] = ebeg + excl;
        dinv[base + t] = rsqrtf((float)(c + 1));
        fill[t] = ebeg + excl;
    }
    __syncthreads();
    for (int e = ebeg + t; e < eend; e += 256) {
        int v = bedge[e];
        int p = atomicAdd(&fill[v >> 17], 1);
        sorted_src[p] = v & 0x1FFFF;
    }
}

// ---------- layer 1 transform: hs1 = bf16((x @ W1) * dinv) ----------
__global__ __launch_bounds__(256) void k_gemm1(const float* __restrict__ x,
                                               const float* __restrict__ W1,
                                               const float* __restrict__ dinv,
                                               unsigned* __restrict__ hs1u, int n) {
    __shared__ float w[FIN * FH];  // 8 KB
    int t = threadIdx.x;
    for (int i = t; i < FIN * FH; i += 256) w[i] = W1[i];
    __syncthreads();
    int r = t >> 4, j = t & 15;
    int row = blockIdx.x * 16 + r;
    if (row >= n) return;
    const float* xr = x + (long long)row * FIN;
    float acc = 0.0f;
#pragma unroll 8
    for (int k = 0; k < FIN; ++k) acc = fmaf(xr[k], w[k * FH + j], acc);
    float v = acc * dinv[row];
    float v_hi = __shfl_xor(v, 1, 64);   // partner feature j^1
    if ((j & 1) == 0) hs1u[row * 8 + (j >> 1)] = pack_bf16x2(v, v_hi);
}

// ---------- layer 1 gather + relu + bias, pre-scaled for layer 2 (bf16 rows) ----------
__global__ __launch_bounds__(256) void k_gather1(const int* __restrict__ rs,
                                                 const int* __restrict__ cnt,
                                                 const int* __restrict__ ss,
                                                 const unsigned* __restrict__ hs1u,
                                                 const float* __restrict__ dinv,
                                                 const float* __restrict__ b1,
                                                 unsigned* __restrict__ h1su, int n) {
    int t = threadIdx.x;
    int lane = t & 63, g8 = lane >> 3, f2 = lane & 7;
    int node = blockIdx.x * 4 + (t >> 6);
    if (node >= n) return;
    int beg = rs[node], end = beg + cnt[node];
    float ax = 0.0f, ay = 0.0f;
    int e = beg + g8;
    for (; e + 8 < end; e += 16) {
        unsigned u0 = hs1u[ss[e] * 8 + f2];
        unsigned u1 = hs1u[ss[e + 8] * 8 + f2];
        float2 p0 = unpack_bf16x2(u0);
        float2 p1 = unpack_bf16x2(u1);
        ax += p0.x + p1.x; ay += p0.y + p1.y;
    }
    if (e < end) {
        float2 p = unpack_bf16x2(hs1u[ss[e] * 8 + f2]);
        ax += p.x; ay += p.y;
    }
#pragma unroll
    for (int off = 8; off <= 32; off <<= 1) {
        ax += __shfl_xor(ax, off, 64);
        ay += __shfl_xor(ay, off, 64);
    }
    float2 s = unpack_bf16x2(hs1u[node * 8 + f2]);  // self-loop
    ax += s.x; ay += s.y;
    float di = dinv[node];
    float v0 = fmaxf(fmaf(di, ax, b1[2 * f2]), 0.0f) * di;
    float v1 = fmaxf(fmaf(di, ay, b1[2 * f2 + 1]), 0.0f) * di;
    if (lane < 8) h1su[node * 8 + f2] = pack_bf16x2(v0, v1);
}

// ---------- layer 2: bf16 gather, fused (g @ W2)*dinv + b2 -> log_softmax ----------
__global__ __launch_bounds__(256) void k_agg2f(const int* __restrict__ rs,
                                               const int* __restrict__ cnt,
                                               const int* __restrict__ ss,
                                               const unsigned* __restrict__ h1su,
                                               const float* __restrict__ dinv,
                                               const float* __restrict__ W2,
                                               const float* __restrict__ b2,
                                               float* __restrict__ out, int n) {
    int t = threadIdx.x;
    int lane = t & 63, g8 = lane >> 3, f2 = lane & 7;
    int node = blockIdx.x * 4 + (t >> 6);
    if (node >= n) return;
    float w[FH];  // W2 column `lane`
#pragma unroll
    for (int j = 0; j < FH; ++j) w[j] = W2[j * FO + lane];
    int beg = rs[node], end = beg + cnt[node];
    float ax = 0.0f, ay = 0.0f;
    int e = beg + g8;
    for (; e + 8 < end; e += 16) {
        unsigned u0 = h1su[ss[e] * 8 + f2];
        unsigned u1 = h1su[ss[e + 8] * 8 + f2];
        float2 p0 = unpack_bf16x2(u0);
        float2 p1 = unpack_bf16x2(u1);
        ax += p0.x + p1.x; ay += p0.y + p1.y;
    }
    if (e < end) {
        float2 p = unpack_bf16x2(h1su[ss[e] * 8 + f2]);
        ax += p.x; ay += p.y;
    }
#pragma unroll
    for (int off = 8; off <= 32; off <<= 1) {
        ax += __shfl_xor(ax, off, 64);
        ay += __shfl_xor(ay, off, 64);
    }
    float2 s = unpack_bf16x2(h1su[node * 8 + f2]);  // self-loop
    ax += s.x; ay += s.y;
    // lane f2 holds pair (g[2f2], g[2f2+1]) in every 8-lane segment; 16 -> 64
    float o = 0.0f;
#pragma unroll
    for (int j = 0; j < 8; ++j) {
        o = fmaf(__shfl(ax, j, 8), w[2 * j], o);
        o = fmaf(__shfl(ay, j, 8), w[2 * j + 1], o);
    }
    float v = fmaf(dinv[node], o, b2[lane]);
    float m = v;
#pragma unroll
    for (int off = 32; off >= 1; off >>= 1) m = fmaxf(m, __shfl_xor(m, off, 64));
    float ex = __expf(v - m);
#pragma unroll
    for (int off = 32; off >= 1; off >>= 1) ex += __shfl_xor(ex, off, 64);
    out[node * FO + lane] = v - m - __logf(ex);
}

extern "C" void kernel_launch(void* const* d_in, const int* in_sizes, int n_in,
                              void* d_out, int out_size, void* d_ws, size_t ws_size,
                              hipStream_t stream) {
    const float* x  = (const float*)d_in[0];
    const int*   ei = (const int*)d_in[1];
    const float* W1 = (const float*)d_in[2];
    const float* b1 = (const float*)d_in[3];
    const float* W2 = (const float*)d_in[4];
    const float* b2 = (const float*)d_in[5];
    float* out = (float*)d_out;

    int N = in_sizes[0] / FIN;   // 100000
    int E = in_sizes[1] / 2;     // 3200000
    const int* src = ei;
    const int* dst = ei + E;
    int nb = (N + GB - 1) / GB;  // 782

    // workspace (4B units): bcnt[1024] | bstart[1025] | bfill[1024] | counts[N]
    //   | row_start[N] | sorted_src[E] | bedge[E] | dinv[N] | hs1u[8N] | h1su[8N]
    int* bcnt       = (int*)d_ws;
    int* bstart     = bcnt + MAXNB;
    int* bfill      = bstart + MAXNB + 1;
    int* counts     = bfill + MAXNB;
    int* row_start  = counts + N;
    int* sorted_src = row_start + N;
    int* bedge      = sorted_src + E;
    float* dinv     = (float*)(bedge + E);
    unsigned* hs1u  = (unsigned*)(dinv + N);
    unsigned* h1su  = hs1u + 8LL * N;

    hipMemsetAsync(bcnt, 0, MAXNB * sizeof(int), stream);
    k_bhist<<<256, 1024, 0, stream>>>(dst, bcnt, E, nb);
    k_bscan<<<1, 1024, 0, stream>>>(bcnt, bstart, bfill, nb);
    k_bscatter<<<(E + CHUNK - 1) / CHUNK, 1024, 0, stream>>>(src, dst, bfill, bedge, E);
    k_nsort<<<nb, 256, 0, stream>>>(bstart, bedge, sorted_src, counts, row_start, dinv, N);

    k_gemm1<<<(N + 15) / 16, 256, 0, stream>>>(x, W1, dinv, hs1u, N);
    k_gather1<<<(N + 3) / 4, 256, 0, stream>>>(row_start, counts, sorted_src, hs1u, dinv, b1, h1su, N);
    k_agg2f<<<(N + 3) / 4, 256, 0, stream>>>(row_start, counts, sorted_src, h1su, dinv, W2, b2, out, N);
}